// Round 1
// 58.637 us; speedup vs baseline: 1.0116x; 1.0116x over previous
//
#include <hip/hip_runtime.h>

// GiniLoss: gini = sum_{i,j} |x_i - x_j| / (2 * n^2 * mu)
// where mu = mean(x - min(x)) + EPS if min(x) < 0 else mean(x) + EPS.
// The min-shift cancels inside |xf_i - xf_j| so the pairwise sum uses raw x.
// n = 8192 -> x fits in 32 KB LDS (every block stages a full copy).
//
// R7: timed region is dominated by the harness's 268 MB workspace poison
// fill (39.4 us @ 85% HBM peak, untouchable). Controllable slice ~20 us =
// kernelA + kernelB + dispatch overhead. This round trims all three:
//  - 256 blocks x 512 threads (was 512x256): same waves/CU (8) and
//    waves/SIMD (2), but half the block prologues and half the LDS
//    staging traffic (each CU stages x once, not twice).
//  - min/sum computed per-block from the 32 row registers every thread
//    already holds (uniform across blocks; removes the block-0 straggler
//    that previously did an extra 8192-elem LDS sweep).
//  - finalize kernel slimmed to a single wave: no LDS, no barrier.
//
// Triangle: W = sum_g sum_{r in G_g} sum_{j>=8g} |x_r - x_j| = T + T_intra,
// S = 2*(W - T_intra). T_intra (28 pairs/group) subtracted by lanes 0..3.
// Block b owns groups (b, 1023-b, 256+b, 767-b): pair window sizes
// complement -> uniform 4100 chunk-iters per block (~8 per thread).

#define EPS 1e-8f

__global__ void __launch_bounds__(512) gini_pair_partial(
    const float* __restrict__ x, float* __restrict__ partials, int n) {
    __shared__ __align__(16) float sm[8192];
    const int nchunks = n >> 2;  // 2048 float4 chunks
    {
        const float4* xv = (const float4*)x;
        float4* smv = (float4*)sm;
        for (int i = threadIdx.x; i < nchunks; i += 512) smv[i] = xv[i];
    }
    __syncthreads();

    const int ngroups = n >> 3;            // 1024 groups of 8 rows
    const int nb = gridDim.x;              // 256
    const int b  = blockIdx.x;
    const int g0 = b;                      // 0 .. 255
    const int g1 = ngroups - 1 - b;        // 1023 .. 768
    const int g2 = nb + b;                 // 256 .. 511
    const int g3 = ngroups - 1 - nb - b;   // 767 .. 512
    const int t  = threadIdx.x;

    float r0[8], r1[8], r2[8], r3[8];
    #pragma unroll
    for (int i = 0; i < 8; ++i) {
        r0[i] = sm[g0 * 8 + i];
        r1[i] = sm[g1 * 8 + i];
        r2[i] = sm[g2 * 8 + i];
        r3[i] = sm[g3 * 8 + i];
    }

    float acc[8];
    #pragma unroll
    for (int i = 0; i < 8; ++i) acc[i] = 0.0f;

    const float4* sm4 = (const float4*)sm;

    // Phase 0: group g0 x columns [8*g0, n) -> chunks [2*g0, nchunks)
    for (int c = 2 * g0 + t; c < nchunks; c += 512) {
        float4 v = sm4[c];
        #pragma unroll
        for (int i = 0; i < 8; ++i)
            acc[i] += (fabsf(r0[i] - v.x) + fabsf(r0[i] - v.y)) +
                      (fabsf(r0[i] - v.z) + fabsf(r0[i] - v.w));
    }
    // Phase 1: group g1
    for (int c = 2 * g1 + t; c < nchunks; c += 512) {
        float4 v = sm4[c];
        #pragma unroll
        for (int i = 0; i < 8; ++i)
            acc[i] += (fabsf(r1[i] - v.x) + fabsf(r1[i] - v.y)) +
                      (fabsf(r1[i] - v.z) + fabsf(r1[i] - v.w));
    }
    // Phase 2: group g2
    for (int c = 2 * g2 + t; c < nchunks; c += 512) {
        float4 v = sm4[c];
        #pragma unroll
        for (int i = 0; i < 8; ++i)
            acc[i] += (fabsf(r2[i] - v.x) + fabsf(r2[i] - v.y)) +
                      (fabsf(r2[i] - v.z) + fabsf(r2[i] - v.w));
    }
    // Phase 3: group g3
    for (int c = 2 * g3 + t; c < nchunks; c += 512) {
        float4 v = sm4[c];
        #pragma unroll
        for (int i = 0; i < 8; ++i)
            acc[i] += (fabsf(r3[i] - v.x) + fabsf(r3[i] - v.y)) +
                      (fabsf(r3[i] - v.z) + fabsf(r3[i] - v.w));
    }

    float a = ((acc[0] + acc[1]) + (acc[2] + acc[3])) +
              ((acc[4] + acc[5]) + (acc[6] + acc[7]));

    // Subtract T_intra for this block's four groups (28 pairs each).
    if (t == 0) {
        float s = 0.0f;
        #pragma unroll
        for (int i = 0; i < 8; ++i)
            #pragma unroll
            for (int j = i + 1; j < 8; ++j) s += fabsf(r0[i] - r0[j]);
        a -= s;
    }
    if (t == 1) {
        float s = 0.0f;
        #pragma unroll
        for (int i = 0; i < 8; ++i)
            #pragma unroll
            for (int j = i + 1; j < 8; ++j) s += fabsf(r1[i] - r1[j]);
        a -= s;
    }
    if (t == 2) {
        float s = 0.0f;
        #pragma unroll
        for (int i = 0; i < 8; ++i)
            #pragma unroll
            for (int j = i + 1; j < 8; ++j) s += fabsf(r2[i] - r2[j]);
        a -= s;
    }
    if (t == 3) {
        float s = 0.0f;
        #pragma unroll
        for (int i = 0; i < 8; ++i)
            #pragma unroll
            for (int j = i + 1; j < 8; ++j) s += fabsf(r3[i] - r3[j]);
        a -= s;
    }

    // Per-block min/sum over this block's 32 rows. The row values are
    // broadcast-identical in every thread, so this is a uniform register
    // computation -- no shuffles, no LDS. Union over blocks covers all x.
    float mn = r0[0];
    float sum = 0.0f;
    #pragma unroll
    for (int i = 0; i < 8; ++i) {
        mn = fminf(fminf(mn, fminf(r0[i], r1[i])), fminf(r2[i], r3[i]));
        sum += (r0[i] + r1[i]) + (r2[i] + r3[i]);
    }

    #pragma unroll
    for (int off = 32; off > 0; off >>= 1) a += __shfl_down(a, off, 64);

    __shared__ float wsum[8];
    if ((t & 63) == 0) wsum[t >> 6] = a;
    __syncthreads();
    if (t == 0) {
        float tot = ((wsum[0] + wsum[1]) + (wsum[2] + wsum[3])) +
                    ((wsum[4] + wsum[5]) + (wsum[6] + wsum[7]));
        partials[b]          = tot;
        partials[nb + b]     = mn;
        partials[2 * nb + b] = sum;
    }
}

// Kernel B: one wave reduces 3*256 partials, finalizes. No LDS, no barrier.
__global__ void __launch_bounds__(64) gini_finalize(
    const float* __restrict__ partials, int nblocks,
    float* __restrict__ out, int n) {
    float psum = 0.0f, pmn = 3.4e38f, ps = 0.0f;
    for (int i = threadIdx.x; i < nblocks; i += 64) {
        psum += partials[i];
        pmn = fminf(pmn, partials[nblocks + i]);
        ps  += partials[2 * nblocks + i];
    }
    #pragma unroll
    for (int off = 32; off > 0; off >>= 1) {
        psum += __shfl_down(psum, off, 64);
        pmn = fminf(pmn, __shfl_down(pmn, off, 64));
        ps  += __shfl_down(ps, off, 64);
    }
    if (threadIdx.x == 0) {
        float sd = 2.0f * psum;
        float shifted_sum = (pmn < 0.0f) ? (ps - (float)n * pmn) : ps;
        float mu = shifted_sum / (float)n + EPS;
        out[0] = sd / (2.0f * (float)n * (float)n * mu);
    }
}

extern "C" void kernel_launch(void* const* d_in, const int* in_sizes, int n_in,
                              void* d_out, int out_size, void* d_ws, size_t ws_size,
                              hipStream_t stream) {
    const float* x = (const float*)d_in[0];
    float* out = (float*)d_out;
    float* partials = (float*)d_ws;
    int n = in_sizes[0];

    int ngroups = n >> 3;          // 1024
    int nblocks = ngroups >> 2;    // 256: block b owns 4 groups (2 pairs)
    gini_pair_partial<<<nblocks, 512, 0, stream>>>(x, partials, n);
    gini_finalize<<<1, 64, 0, stream>>>(partials, nblocks, out, n);
}